// Round 7
// baseline (1364.247 us; speedup 1.0000x reference)
//
#include <hip/hip_runtime.h>

// BasicNCA: 16 sequential steps of (11x11 SAME conv -> per-pixel MLP 1->10->10->1
// -> residual add -> clip[0,1]) on (16,1,256,256) fp32.
// Output = all 17 states: out[t] slab, t=0..16, slab = 16*256*256 floats.
//
// R5 post-mortem: persistent kernels (global barrier / neighbor flags / coherent
// accesses) all land at ~360 us vs 288 us for the plain 17-launch chain -> the
// per-step device-wide coherence cost exceeds the launch gaps. This version
// keeps the launch-chained structure (cached loads/stores, no fences) and
// halves the dominant launch-gap cost via TEMPORAL FUSION: each kernel performs
// TWO NCA steps using redundant halo compute (stage halo-10 tile of slab k,
// compute step k+1 on the 26x74 extended region in LDS, then step k+2 on the
// 16x64 interior; write both slabs). 8 launches total (t=0 copy folded into
// kernel 0). Step-(k+1) LDS values outside the image are explicitly zeroed
// (zero-pad is NOT a fixed point of the MLP: y(0) != 0).

#define HH 256
#define WW 256
#define BB 16
#define TH 16
#define TW 64
// step-A (k+1) region: halo 5 around the 16x64 interior
#define AH 26          // TH + 10
#define AWV 74         // TW + 10 valid cols
// staged slab-k region: halo 10
#define S0H 36         // TH + 20
#define S0WV 84        // TW + 20 valid cols
#define S0P 92         // padded stride (368B, 16B-aligned rows; chunk reads stay in-bounds)
#define S1P 80         // s1 stride (320B, 16B-aligned rows)
#define SLAB (BB * HH * WW)

// ---------------- PWL precompute: c+ = relu(w1) @ w2^T, c- = min(w1,0) @ w2^T ----
__device__ __forceinline__ void mlp_precompute(
    const float* __restrict__ w1, const float* __restrict__ b1,
    const float* __restrict__ w2, bool& fast, float (&cp)[10], float (&cn)[10]) {
    fast = true;
#pragma unroll
    for (int i = 0; i < 10; ++i) fast = fast && (b1[i] == 0.f);
#pragma unroll
    for (int o = 0; o < 10; ++o) { cp[o] = 0.f; cn[o] = 0.f; }
    if (fast) {
#pragma unroll
        for (int i = 0; i < 10; ++i) {
            float wi = w1[i];
            float p = fmaxf(wi, 0.f), n = fminf(wi, 0.f);
#pragma unroll
            for (int o = 0; o < 10; ++o) {
                cp[o] = fmaf(p, w2[o * 10 + i], cp[o]);
                cn[o] = fmaf(n, w2[o * 10 + i], cn[o]);
            }
        }
    }
}

// MLP + residual + clip for one pixel (fast PWL path or exact fallback)
__device__ __forceinline__ float mlp_px(
    float v, float xc, bool fast, const float (&cp)[10], const float (&cn)[10],
    const float* __restrict__ w1, const float* __restrict__ b1,
    const float* __restrict__ w2, const float* __restrict__ b2,
    const float* __restrict__ w3, float b3v) {
    float y = b3v;
    if (fast) {
        bool pos = (v >= 0.f);
#pragma unroll
        for (int o = 0; o < 10; ++o) {
            float c = pos ? cp[o] : cn[o];
            float a = fmaf(v, c, b2[o]);
            y = fmaf(fmaxf(a, 0.f), w3[o], y);
        }
    } else {
        float h1[10];
#pragma unroll
        for (int i = 0; i < 10; ++i) h1[i] = fmaxf(fmaf(v, w1[i], b1[i]), 0.f);
#pragma unroll
        for (int o = 0; o < 10; ++o) {
            float a = b2[o];
#pragma unroll
            for (int i = 0; i < 10; ++i) a = fmaf(h1[i], w2[o * 10 + i], a);
            y = fmaf(fmaxf(a, 0.f), w3[o], y);
        }
    }
    return fminf(fmaxf(xc + y, 0.f), 1.f);
}

// ---------------- fused 2-step kernel ----------------
__global__ __launch_bounds__(256, 4) void nca_step2(
    const float* __restrict__ src, float* __restrict__ dst1,
    float* __restrict__ dst2, float* __restrict__ t0,
    const float* __restrict__ Kk,
    const float* __restrict__ w1, const float* __restrict__ b1,
    const float* __restrict__ w2, const float* __restrict__ b2,
    const float* __restrict__ w3, const float* __restrict__ b3) {
    __shared__ __align__(16) float s0[S0H * S0P];  // slab k, halo 10
    __shared__ __align__(16) float s1[AH * S1P];   // step k+1, halo 5 (+junk pad)

    const int tid = threadIdx.x;
    const int b   = blockIdx.z;
    const int gy0 = blockIdx.y * TH;
    const int gx0 = blockIdx.x * TW;
    const float* img = src + b * HH * WW;
    const float b3v = b3[0];

    bool fast; float cp[10], cn[10];
    mlp_precompute(w1, b1, w2, fast, cp, cn);

    // ---- stage halo-10 tile of slab k (zero pad = SAME) ----
    for (int i = tid; i < S0H * S0WV; i += 256) {
        int r = i / S0WV, c = i - r * S0WV;
        int gy = gy0 - 10 + r, gx = gx0 - 10 + c;
        float v = 0.f;
        if (gy >= 0 && gy < HH && gx >= 0 && gx < WW) v = img[gy * WW + gx];
        s0[r * S0P + c] = v;
    }
    __syncthreads();

    // ---- t=0 slab: write input interior once (kernel 0 only) ----
    if (t0) {
        const int txc = tid & 15, tyc = tid >> 4;
        const float* c0 = &s0[(tyc + 10) * S0P + 10 + txc * 4];
        float* o0 = t0 + b * HH * WW + (gy0 + tyc) * WW + gx0 + txc * 4;
        *(float4*)o0 = make_float4(c0[0], c0[1], c0[2], c0[3]);
    }

    // ---- step A: compute step k+1 on 26 x 74 extended region -> s1 ----
    // work item = (r1, c8): 8-px chunk at s1 row r1, cols c8*8..c8*8+7
    for (int it = tid; it < AH * 10; it += 256) {
        const int r1 = it / 10, c8 = it - r1 * 10;
        const int c1 = c8 * 8;
        float acc[8];
#pragma unroll
        for (int j = 0; j < 8; ++j) acc[j] = 0.f;
        float xc[8];
#pragma unroll
        for (int ky = 0; ky < 11; ++ky) {
            const float* row = &s0[(r1 + ky) * S0P + c1];
            float win[20];
            *(float4*)(win + 0)  = *(const float4*)(row + 0);
            *(float4*)(win + 4)  = *(const float4*)(row + 4);
            *(float4*)(win + 8)  = *(const float4*)(row + 8);
            *(float4*)(win + 12) = *(const float4*)(row + 12);
            *(float4*)(win + 16) = *(const float4*)(row + 16);
            if (ky == 5) {
#pragma unroll
                for (int j = 0; j < 8; ++j) xc[j] = win[5 + j];  // residual source
            }
#pragma unroll
            for (int kx = 0; kx < 11; ++kx) {
                float kv = Kk[ky * 11 + kx];
#pragma unroll
                for (int j = 0; j < 8; ++j)
                    acc[j] = fmaf(win[kx + j], kv, acc[j]);
            }
        }
        const int gy = gy0 - 5 + r1;
        const bool rv = (gy >= 0 && gy < HH);
        float* s1row = &s1[r1 * S1P + c1];
#pragma unroll
        for (int j = 0; j < 8; ++j) {
            int gx = gx0 - 5 + c1 + j;
            float r = mlp_px(acc[j], xc[j], fast, cp, cn, w1, b1, w2, b2, w3, b3v);
            // zero-pad semantics for step k+1: outside image -> 0
            s1row[j] = (rv && gx >= 0 && gx < WW) ? r : 0.f;
        }
    }
    __syncthreads();

    // ---- write slab k+1 interior (from s1) + step B: compute step k+2 ----
    const int tx = tid & 15, ty = tid >> 4;
    const int x0 = tx * 4;

    {   // slab k+1: own 16x64 region = s1 rows ty+5, cols x0+5..x0+8
        const float* c1r = &s1[(ty + 5) * S1P + x0 + 5];
        float* o1 = dst1 + b * HH * WW + (gy0 + ty) * WW + gx0 + x0;
        *(float4*)o1 = make_float4(c1r[0], c1r[1], c1r[2], c1r[3]);
    }

    float acc0 = 0.f, acc1 = 0.f, acc2 = 0.f, acc3 = 0.f;
#pragma unroll
    for (int ky = 0; ky < 11; ++ky) {
        const float* row = &s1[(ty + ky) * S1P + x0];
        float win[16];
        *(float4*)(win + 0)  = *(const float4*)(row + 0);
        *(float4*)(win + 4)  = *(const float4*)(row + 4);
        *(float4*)(win + 8)  = *(const float4*)(row + 8);
        *(float2*)(win + 12) = *(const float2*)(row + 12);
#pragma unroll
        for (int kx = 0; kx < 11; ++kx) {
            float kv = Kk[ky * 11 + kx];
            acc0 = fmaf(win[kx + 0], kv, acc0);
            acc1 = fmaf(win[kx + 1], kv, acc1);
            acc2 = fmaf(win[kx + 2], kv, acc2);
            acc3 = fmaf(win[kx + 3], kv, acc3);
        }
    }
    float vacc[4] = {acc0, acc1, acc2, acc3};
    float res[4];
#pragma unroll
    for (int p = 0; p < 4; ++p) {
        float xc = s1[(ty + 5) * S1P + x0 + 5 + p];
        res[p] = mlp_px(vacc[p], xc, fast, cp, cn, w1, b1, w2, b2, w3, b3v);
    }
    float* o2 = dst2 + b * HH * WW + (gy0 + ty) * WW + gx0 + x0;
    *(float4*)o2 = make_float4(res[0], res[1], res[2], res[3]);
}

extern "C" void kernel_launch(void* const* d_in, const int* in_sizes, int n_in,
                              void* d_out, int out_size, void* d_ws, size_t ws_size,
                              hipStream_t stream) {
    const float* x  = (const float*)d_in[0];
    const float* Kk = (const float*)d_in[1];
    const float* w1 = (const float*)d_in[2];
    const float* b1 = (const float*)d_in[3];
    const float* w2 = (const float*)d_in[4];
    const float* b2 = (const float*)d_in[5];
    const float* w3 = (const float*)d_in[6];
    const float* b3 = (const float*)d_in[7];
    float* out = (float*)d_out;

    dim3 grid(WW / TW, HH / TH, BB);  // 4 x 16 x 16 = 1024 blocks
    // 8 fused kernels: k = 0,2,...,14; kernel 0 also writes the t=0 slab.
    for (int k = 0; k < 16; k += 2) {
        const float* src = (k == 0) ? x : out + (size_t)k * SLAB;
        nca_step2<<<grid, 256, 0, stream>>>(
            src,
            out + (size_t)(k + 1) * SLAB,
            out + (size_t)(k + 2) * SLAB,
            (k == 0) ? out : nullptr,
            Kk, w1, b1, w2, b2, w3, b3);
    }
}

// Round 8
// 414.883 us; speedup vs baseline: 3.2883x; 3.2883x over previous
//
#include <hip/hip_runtime.h>

// BasicNCA: 16 sequential steps of (11x11 SAME conv -> per-pixel MLP 1->10->10->1
// -> residual add -> clip[0,1]) on (16,1,256,256) fp32.
// Output = all 17 states: out[t] slab, t=0..16, slab = 16*256*256 floats.
//
// Temporal fusion (2 steps/kernel, 8 launches, redundant halo compute).
// R7 post-mortem: the 8-px step-A chunks (win[20]+acc[8]+xc[8]) blew the
// 64-VGPR allocation -> massive scratch spills (FETCH 373 MB, WRITE 203 MB per
// dispatch, 164 us each, pure spill-bound). This version restores the PROVEN
// register footprint: step A uses 4-px chunks with the exact win[16]+acc[4]
// pattern of the verified single-step kernel (60 VGPR, no spill), and drops the
// min-occupancy launch-bounds hint (launch-chained kernels need no co-residency).

#define HH 256
#define WW 256
#define BB 16
#define TH 16
#define TW 64
// step-A (k+1) region: halo 5 around the 16x64 interior
#define AH 26          // TH + 10
#define AWV 74         // TW + 10 valid cols
#define ANW 19         // ceil(74/4) 4-px chunks per row
// staged slab-k region: halo 10
#define S0H 36         // TH + 20
#define S0WV 84        // TW + 20 valid cols
#define S0P 92         // padded stride (368B, 16B-aligned rows; win reads stay in-bounds)
#define S1P 80         // s1 stride (320B, 16B-aligned rows)
#define SLAB (BB * HH * WW)

// ---------------- PWL precompute: c+ = relu(w1) @ w2^T, c- = min(w1,0) @ w2^T ----
__device__ __forceinline__ void mlp_precompute(
    const float* __restrict__ w1, const float* __restrict__ b1,
    const float* __restrict__ w2, bool& fast, float (&cp)[10], float (&cn)[10]) {
    fast = true;
#pragma unroll
    for (int i = 0; i < 10; ++i) fast = fast && (b1[i] == 0.f);
#pragma unroll
    for (int o = 0; o < 10; ++o) { cp[o] = 0.f; cn[o] = 0.f; }
    if (fast) {
#pragma unroll
        for (int i = 0; i < 10; ++i) {
            float wi = w1[i];
            float p = fmaxf(wi, 0.f), n = fminf(wi, 0.f);
#pragma unroll
            for (int o = 0; o < 10; ++o) {
                cp[o] = fmaf(p, w2[o * 10 + i], cp[o]);
                cn[o] = fmaf(n, w2[o * 10 + i], cn[o]);
            }
        }
    }
}

// MLP + residual + clip for one pixel (fast PWL path or exact fallback)
__device__ __forceinline__ float mlp_px(
    float v, float xc, bool fast, const float (&cp)[10], const float (&cn)[10],
    const float* __restrict__ w1, const float* __restrict__ b1,
    const float* __restrict__ w2, const float* __restrict__ b2,
    const float* __restrict__ w3, float b3v) {
    float y = b3v;
    if (fast) {
        bool pos = (v >= 0.f);
#pragma unroll
        for (int o = 0; o < 10; ++o) {
            float c = pos ? cp[o] : cn[o];
            float a = fmaf(v, c, b2[o]);
            y = fmaf(fmaxf(a, 0.f), w3[o], y);
        }
    } else {
        float h1[10];
#pragma unroll
        for (int i = 0; i < 10; ++i) h1[i] = fmaxf(fmaf(v, w1[i], b1[i]), 0.f);
#pragma unroll
        for (int o = 0; o < 10; ++o) {
            float a = b2[o];
#pragma unroll
            for (int i = 0; i < 10; ++i) a = fmaf(h1[i], w2[o * 10 + i], a);
            y = fmaf(fmaxf(a, 0.f), w3[o], y);
        }
    }
    return fminf(fmaxf(xc + y, 0.f), 1.f);
}

// 11x11 conv on 4 consecutive pixels from LDS row base (proven low-VGPR pattern)
__device__ __forceinline__ void conv4(const float* sbase, int stride,
                                      const float* __restrict__ Kk,
                                      float (&acc)[4]) {
    acc[0] = acc[1] = acc[2] = acc[3] = 0.f;
#pragma unroll
    for (int ky = 0; ky < 11; ++ky) {
        const float* row = sbase + ky * stride;
        float win[16];
        *(float4*)(win + 0)  = *(const float4*)(row + 0);
        *(float4*)(win + 4)  = *(const float4*)(row + 4);
        *(float4*)(win + 8)  = *(const float4*)(row + 8);
        *(float2*)(win + 12) = *(const float2*)(row + 12);
#pragma unroll
        for (int kx = 0; kx < 11; ++kx) {
            float kv = Kk[ky * 11 + kx];  // wave-uniform -> s_load
            acc[0] = fmaf(win[kx + 0], kv, acc[0]);
            acc[1] = fmaf(win[kx + 1], kv, acc[1]);
            acc[2] = fmaf(win[kx + 2], kv, acc[2]);
            acc[3] = fmaf(win[kx + 3], kv, acc[3]);
        }
    }
}

// ---------------- fused 2-step kernel ----------------
__global__ __launch_bounds__(256) void nca_step2(
    const float* __restrict__ src, float* __restrict__ dst1,
    float* __restrict__ dst2, float* __restrict__ t0,
    const float* __restrict__ Kk,
    const float* __restrict__ w1, const float* __restrict__ b1,
    const float* __restrict__ w2, const float* __restrict__ b2,
    const float* __restrict__ w3, const float* __restrict__ b3) {
    __shared__ __align__(16) float s0[S0H * S0P];  // slab k, halo 10
    __shared__ __align__(16) float s1[AH * S1P];   // step k+1, halo 5 (+junk pad)

    const int tid = threadIdx.x;
    const int b   = blockIdx.z;
    const int gy0 = blockIdx.y * TH;
    const int gx0 = blockIdx.x * TW;
    const float* img = src + b * HH * WW;
    const float b3v = b3[0];

    bool fast; float cp[10], cn[10];
    mlp_precompute(w1, b1, w2, fast, cp, cn);

    // ---- stage halo-10 tile of slab k (zero pad = SAME) ----
    for (int i = tid; i < S0H * S0WV; i += 256) {
        int r = i / S0WV, c = i - r * S0WV;
        int gy = gy0 - 10 + r, gx = gx0 - 10 + c;
        float v = 0.f;
        if (gy >= 0 && gy < HH && gx >= 0 && gx < WW) v = img[gy * WW + gx];
        s0[r * S0P + c] = v;
    }
    __syncthreads();

    // ---- t=0 slab: write input interior once (kernel 0 only) ----
    if (t0) {
        const int txc = tid & 15, tyc = tid >> 4;
        const float* c0 = &s0[(tyc + 10) * S0P + 10 + txc * 4];
        float* o0 = t0 + b * HH * WW + (gy0 + tyc) * WW + gx0 + txc * 4;
        *(float4*)o0 = make_float4(c0[0], c0[1], c0[2], c0[3]);
    }

    // ---- step A: compute step k+1 on 26 x 74 region -> s1 (4-px chunks) ----
    for (int it = tid; it < AH * ANW; it += 256) {
        const int r1 = it / ANW, c4 = it - r1 * ANW;
        const int c1 = c4 * 4;
        float acc[4];
        conv4(&s0[r1 * S0P + c1], S0P, Kk, acc);
        const int gy = gy0 - 5 + r1;
        const bool rv = (gy >= 0 && gy < HH);
        float* s1row = &s1[r1 * S1P + c1];
#pragma unroll
        for (int j = 0; j < 4; ++j) {
            float xc = s0[(r1 + 5) * S0P + c1 + 5 + j];
            float r = mlp_px(acc[j], xc, fast, cp, cn, w1, b1, w2, b2, w3, b3v);
            int gx = gx0 - 5 + c1 + j;
            // zero-pad semantics for step k+1: outside image -> 0
            s1row[j] = (rv && gx >= 0 && gx < WW) ? r : 0.f;
        }
    }
    __syncthreads();

    // ---- write slab k+1 interior (from s1) + step B: compute step k+2 ----
    const int tx = tid & 15, ty = tid >> 4;
    const int x0 = tx * 4;

    {   // slab k+1: own 16x64 region = s1 rows ty+5, cols x0+5..x0+8
        const float* c1r = &s1[(ty + 5) * S1P + x0 + 5];
        float* o1 = dst1 + b * HH * WW + (gy0 + ty) * WW + gx0 + x0;
        *(float4*)o1 = make_float4(c1r[0], c1r[1], c1r[2], c1r[3]);
    }

    float acc[4];
    conv4(&s1[ty * S1P + x0], S1P, Kk, acc);
    float res[4];
#pragma unroll
    for (int p = 0; p < 4; ++p) {
        float xc = s1[(ty + 5) * S1P + x0 + 5 + p];
        res[p] = mlp_px(acc[p], xc, fast, cp, cn, w1, b1, w2, b2, w3, b3v);
    }
    float* o2 = dst2 + b * HH * WW + (gy0 + ty) * WW + gx0 + x0;
    *(float4*)o2 = make_float4(res[0], res[1], res[2], res[3]);
}

extern "C" void kernel_launch(void* const* d_in, const int* in_sizes, int n_in,
                              void* d_out, int out_size, void* d_ws, size_t ws_size,
                              hipStream_t stream) {
    const float* x  = (const float*)d_in[0];
    const float* Kk = (const float*)d_in[1];
    const float* w1 = (const float*)d_in[2];
    const float* b1 = (const float*)d_in[3];
    const float* w2 = (const float*)d_in[4];
    const float* b2 = (const float*)d_in[5];
    const float* w3 = (const float*)d_in[6];
    const float* b3 = (const float*)d_in[7];
    float* out = (float*)d_out;

    dim3 grid(WW / TW, HH / TH, BB);  // 4 x 16 x 16 = 1024 blocks
    // 8 fused kernels: k = 0,2,...,14; kernel 0 also writes the t=0 slab.
    for (int k = 0; k < 16; k += 2) {
        const float* src = (k == 0) ? x : out + (size_t)k * SLAB;
        nca_step2<<<grid, 256, 0, stream>>>(
            src,
            out + (size_t)(k + 1) * SLAB,
            out + (size_t)(k + 2) * SLAB,
            (k == 0) ? out : nullptr,
            Kk, w1, b1, w2, b2, w3, b3);
    }
}

// Round 9
// 403.447 us; speedup vs baseline: 3.3815x; 1.0283x over previous
//
#include <hip/hip_runtime.h>

// BasicNCA: 16 sequential steps of (11x11 SAME conv -> per-pixel MLP 1->10->10->1
// -> residual add -> clip[0,1]) on (16,1,256,256) fp32.
// Output = all 17 states: out[t] slab, t=0..16, slab = 16*256*256 floats.
//
// R8 post-mortem: launch gap is only ~3.4 us (wall - sum(kernels)); the
// single-step kernel (~13.4 us) dominates the 288 us baseline, and 2-step
// fusion loses (redundant halo conv 1.44x + occupancy drop -> 24 us/step).
// This version: plain 16-launch chain (proven fastest structure) with
// (a) exact PWL collapse of the MLP (b1==0, runtime-checked; cuts MLP VALU
//     ~3.5x; verified exact in R5/R7/R8, absmax unchanged 0.0039),
// (b) t=0 slab written by kernel 0 from its staged tile (one less launch),
// (c) the original proven 60-VGPR conv structure, untouched.

#define HH 256
#define WW 256
#define BB 16
#define TH 16
#define TW 64
#define SH (TH + 10)   // 26
#define SW (TW + 10)   // 74
#define SWP 76         // padded LDS stride (16B-aligned rows)
#define SLAB (BB * HH * WW)

// ---------------- PWL precompute: c+ = relu(w1) @ w2^T, c- = min(w1,0) @ w2^T ----
__device__ __forceinline__ void mlp_precompute(
    const float* __restrict__ w1, const float* __restrict__ b1,
    const float* __restrict__ w2, bool& fast, float (&cp)[10], float (&cn)[10]) {
    fast = true;
#pragma unroll
    for (int i = 0; i < 10; ++i) fast = fast && (b1[i] == 0.f);
#pragma unroll
    for (int o = 0; o < 10; ++o) { cp[o] = 0.f; cn[o] = 0.f; }
    if (fast) {
#pragma unroll
        for (int i = 0; i < 10; ++i) {
            float wi = w1[i];
            float p = fmaxf(wi, 0.f), n = fminf(wi, 0.f);
#pragma unroll
            for (int o = 0; o < 10; ++o) {
                cp[o] = fmaf(p, w2[o * 10 + i], cp[o]);
                cn[o] = fmaf(n, w2[o * 10 + i], cn[o]);
            }
        }
    }
}

// MLP + residual + clip for one pixel (fast PWL path or exact fallback)
__device__ __forceinline__ float mlp_px(
    float v, float xc, bool fast, const float (&cp)[10], const float (&cn)[10],
    const float* __restrict__ w1, const float* __restrict__ b1,
    const float* __restrict__ w2, const float* __restrict__ b2,
    const float* __restrict__ w3, float b3v) {
    float y = b3v;
    if (fast) {
        // exact: h2_o = relu(v * c_o^{sign(v)} + b2_o);  h1 = relu(v*w1) with b1==0
        bool pos = (v >= 0.f);
#pragma unroll
        for (int o = 0; o < 10; ++o) {
            float c = pos ? cp[o] : cn[o];
            float a = fmaf(v, c, b2[o]);
            y = fmaf(fmaxf(a, 0.f), w3[o], y);
        }
    } else {
        float h1[10];
#pragma unroll
        for (int i = 0; i < 10; ++i) h1[i] = fmaxf(fmaf(v, w1[i], b1[i]), 0.f);
#pragma unroll
        for (int o = 0; o < 10; ++o) {
            float a = b2[o];
#pragma unroll
            for (int i = 0; i < 10; ++i) a = fmaf(h1[i], w2[o * 10 + i], a);
            y = fmaf(fmaxf(a, 0.f), w3[o], y);
        }
    }
    return fminf(fmaxf(xc + y, 0.f), 1.f);
}

// ---------------- single NCA step (one tile per block) ----------------
__global__ __launch_bounds__(256) void nca_step(
    const float* __restrict__ src, float* __restrict__ dst,
    float* __restrict__ t0,
    const float* __restrict__ Kk,
    const float* __restrict__ w1, const float* __restrict__ b1,
    const float* __restrict__ w2, const float* __restrict__ b2,
    const float* __restrict__ w3, const float* __restrict__ b3) {
    __shared__ __align__(16) float s[SH * SWP];

    const int tid = threadIdx.x;
    const int b   = blockIdx.z;
    const int gy0 = blockIdx.y * TH;
    const int gx0 = blockIdx.x * TW;
    const float* img = src + b * HH * WW;
    const float b3v = b3[0];

    bool fast; float cp[10], cn[10];
    mlp_precompute(w1, b1, w2, fast, cp, cn);

    // ---- stage halo'd tile (zero pad = SAME) ----
    for (int i = tid; i < SH * SW; i += 256) {
        int r = i / SW, c = i - r * SW;
        int gy = gy0 - 5 + r, gx = gx0 - 5 + c;
        float v = 0.f;
        if (gy >= 0 && gy < HH && gx >= 0 && gx < WW) v = img[gy * WW + gx];
        s[r * SWP + c] = v;
    }
    __syncthreads();

    const int tx = tid & 15, ty = tid >> 4;
    const int x0 = tx * 4;  // 4 consecutive output pixels per thread

    // ---- t=0 slab: write input interior once (kernel 0 only) ----
    if (t0) {
        const float* c0 = &s[(ty + 5) * SWP + x0 + 5];
        float* o0 = t0 + b * HH * WW + (gy0 + ty) * WW + gx0 + x0;
        *(float4*)o0 = make_float4(c0[0], c0[1], c0[2], c0[3]);
    }

    // ---- 11x11 conv via 14-wide register sliding window per ky ----
    float acc0 = 0.f, acc1 = 0.f, acc2 = 0.f, acc3 = 0.f;
#pragma unroll
    for (int ky = 0; ky < 11; ++ky) {
        const float* row = &s[(ty + ky) * SWP + x0];
        float win[16];
        *(float4*)(win + 0)  = *(const float4*)(row + 0);
        *(float4*)(win + 4)  = *(const float4*)(row + 4);
        *(float4*)(win + 8)  = *(const float4*)(row + 8);
        *(float2*)(win + 12) = *(const float2*)(row + 12);
#pragma unroll
        for (int kx = 0; kx < 11; ++kx) {
            float kv = Kk[ky * 11 + kx];  // wave-uniform -> s_load
            acc0 = fmaf(win[kx + 0], kv, acc0);
            acc1 = fmaf(win[kx + 1], kv, acc1);
            acc2 = fmaf(win[kx + 2], kv, acc2);
            acc3 = fmaf(win[kx + 3], kv, acc3);
        }
    }

    // ---- per-pixel MLP + residual + clip ----
    float vacc[4] = {acc0, acc1, acc2, acc3};
    float res[4];
#pragma unroll
    for (int p = 0; p < 4; ++p) {
        float xc = s[(ty + 5) * SWP + x0 + 5 + p];
        res[p] = mlp_px(vacc[p], xc, fast, cp, cn, w1, b1, w2, b2, w3, b3v);
    }

    float* orow = dst + b * HH * WW + (gy0 + ty) * WW + gx0 + x0;
    *(float4*)orow = make_float4(res[0], res[1], res[2], res[3]);
}

extern "C" void kernel_launch(void* const* d_in, const int* in_sizes, int n_in,
                              void* d_out, int out_size, void* d_ws, size_t ws_size,
                              hipStream_t stream) {
    const float* x  = (const float*)d_in[0];
    const float* Kk = (const float*)d_in[1];
    const float* w1 = (const float*)d_in[2];
    const float* b1 = (const float*)d_in[3];
    const float* w2 = (const float*)d_in[4];
    const float* b2 = (const float*)d_in[5];
    const float* w3 = (const float*)d_in[6];
    const float* b3 = (const float*)d_in[7];
    float* out = (float*)d_out;

    dim3 grid(WW / TW, HH / TH, BB);  // 4 x 16 x 16 = 1024 blocks
    // 16 launches; kernel 0 reads x and also writes the t=0 slab.
    for (int k = 0; k < 16; ++k) {
        const float* src = (k == 0) ? x : out + (size_t)k * SLAB;
        nca_step<<<grid, 256, 0, stream>>>(
            src,
            out + (size_t)(k + 1) * SLAB,
            (k == 0) ? out : nullptr,
            Kk, w1, b1, w2, b2, w3, b3);
    }
}